// Round 6
// baseline (949.771 us; speedup 1.0000x reference)
//
#include <hip/hip_runtime.h>
#include <hip/hip_bf16.h>
#include <stdint.h>

typedef __bf16 bf16;
typedef __bf16 bf16x8 __attribute__((ext_vector_type(8)));
typedef __bf16 bf16x4 __attribute__((ext_vector_type(4)));
typedef float  f32x4  __attribute__((ext_vector_type(4)));

#define LDS_PTR(p) ((__attribute__((address_space(3))) uint32_t*)(p))
#define GLB_PTR(p) ((const __attribute__((address_space(1))) uint32_t*)(p))

static constexpr int BATCH = 4, SEQ = 4096, DMODEL = 1024;
static constexpr int DI = 2048;
static constexpr int MTOK = BATCH * SEQ;   // 16384 tokens

enum { EPI_SPLIT = 0, EPI_PLAIN = 1, EPI_ZGATE = 2, EPI_RES = 3, EPI_F32S = 4 };

// ---------------------------------------------------------------------------
// 128x128-tile bf16 GEMM (m97 structure) — the proven workhorse (~780 TF).
// SPLITK: blockIdx.x = K-split, blockIdx.y = m-tile, blockIdx.z = n-tile.
// EPI_ZGATE fuses the rank-16 z_a correction + gate into the epilogue:
//   y2[m,n] = gate[m,n] * (acc + bias_z[n] + sum_s s16[m,s]*T2t[n,s])
//   (s16f passed via outf, T2t via resid, bias_z via bias; zbuf write-only)
// ---------------------------------------------------------------------------
template <int EPI, bool SPLITK = false>
__global__ __launch_bounds__(256) void gemm_bt(
    const bf16* __restrict__ Aact, const bf16* __restrict__ W,
    const float* __restrict__ bias,
    bf16* __restrict__ out0, bf16* __restrict__ out1,
    const bf16* __restrict__ gate,
    float* __restrict__ outf, const float* __restrict__ resid,
    int N, int K, int ldC, int col_off)
{
  __shared__ __align__(16) bf16 sA[128 * 64];
  __shared__ __align__(16) bf16 sB[128 * 64];
  const int tid  = threadIdx.x;
  int n0, m0, kbeg, kend;
  size_t out_off = 0;
  if (SPLITK) {
    n0 = blockIdx.z * 128;
    m0 = blockIdx.y * 128;
    const int kh = K / gridDim.x;
    kbeg = blockIdx.x * kh; kend = kbeg + kh;
    out_off = (EPI == EPI_F32S) ? (size_t)blockIdx.x * (size_t)col_off
                                : (size_t)blockIdx.x * ((size_t)MTOK * 128);
  } else {
    const int nT  = gridDim.x;
    const int lin = blockIdx.y * nT + blockIdx.x;
    const int grp = lin / (8 * nT);
    const int within = lin - grp * (8 * nT);
    n0 = (within >> 3) * 128;
    m0 = (grp * 8 + (within & 7)) * 128;
    kbeg = 0; kend = K;
  }
  const int lane = tid & 63;
  const int wv   = tid >> 6;
  const int wr   = wv >> 1, wc = wv & 1;
  const int l15  = lane & 15, quad = lane >> 4;

  f32x4 acc[4][4];
#pragma unroll
  for (int i = 0; i < 4; ++i)
#pragma unroll
    for (int j = 0; j < 4; ++j) acc[i][j] = (f32x4){0.f, 0.f, 0.f, 0.f};

  int rr[4], cb[4];
#pragma unroll
  for (int j = 0; j < 4; ++j) {
    const int s = tid + j * 256;
    rr[j] = s >> 3;
    cb[j] = ((s & 7) ^ (rr[j] & 7)) * 16;
  }

  const char* gA = (const char*)(Aact + (size_t)m0 * K);
  const char* gW = (const char*)(W + (size_t)n0 * K);

  for (int k0 = kbeg; k0 < kend; k0 += 64) {
    if (k0 != kbeg) __syncthreads();
#pragma unroll
    for (int j = 0; j < 4; ++j)
      __builtin_amdgcn_global_load_lds(GLB_PTR(gA + ((size_t)rr[j] * K + k0) * 2 + cb[j]),
                                       LDS_PTR(sA + (tid + j * 256) * 8), 16, 0, 0);
#pragma unroll
    for (int j = 0; j < 4; ++j)
      __builtin_amdgcn_global_load_lds(GLB_PTR(gW + ((size_t)rr[j] * K + k0) * 2 + cb[j]),
                                       LDS_PTR(sB + (tid + j * 256) * 8), 16, 0, 0);
    __syncthreads();

#pragma unroll
    for (int h = 0; h < 2; ++h) {
      bf16x8 av[4], bv[4];
#pragma unroll
      for (int t = 0; t < 4; ++t) {
        const int Ra = wr * 64 + t * 16 + l15;
        const int Rb = wc * 64 + t * 16 + l15;
        const int cc = h * 4 + quad;
        av[t] = *(const bf16x8*)(sA + (Ra * 8 + (cc ^ (Ra & 7))) * 8);
        bv[t] = *(const bf16x8*)(sB + (Rb * 8 + (cc ^ (Rb & 7))) * 8);
      }
#pragma unroll
      for (int i = 0; i < 4; ++i)
#pragma unroll
        for (int j = 0; j < 4; ++j)
          acc[i][j] = __builtin_amdgcn_mfma_f32_16x16x32_bf16(av[i], bv[j], acc[i][j], 0, 0, 0);
    }
  }

  // ---- EPI_ZGATE: stage s16[m0..m0+127][16] and T2t[n0..n0+127][16] in LDS
  float* sS = (float*)sA;    // padded [128][17]
  float* sT = (float*)sB;    // padded [128][17]
  float tt[4][16];
  if (EPI == EPI_ZGATE) {
    __syncthreads();   // all waves done with K-loop LDS reads
    const float* s16f = outf;         // [MTOK][16]
    const float* T2   = resid;        // [2048][16]
    {
      const float4 a0 = ((const float4*)(s16f + (size_t)m0 * 16))[tid * 2];
      const float4 a1 = ((const float4*)(s16f + (size_t)m0 * 16))[tid * 2 + 1];
      const float4 b0 = ((const float4*)(T2 + (size_t)n0 * 16))[tid * 2];
      const float4 b1 = ((const float4*)(T2 + (size_t)n0 * 16))[tid * 2 + 1];
      const int i0 = tid * 8;
      const float av_[8] = {a0.x, a0.y, a0.z, a0.w, a1.x, a1.y, a1.z, a1.w};
      const float bv_[8] = {b0.x, b0.y, b0.z, b0.w, b1.x, b1.y, b1.z, b1.w};
#pragma unroll
      for (int e = 0; e < 8; ++e) {
        const int idx = i0 + e;
        sS[(idx >> 4) * 17 + (idx & 15)] = av_[e];
        sT[(idx >> 4) * 17 + (idx & 15)] = bv_[e];
      }
    }
    __syncthreads();
#pragma unroll
    for (int j = 0; j < 4; ++j) {
      const int nloc = wc * 64 + j * 16 + l15;
#pragma unroll
      for (int s = 0; s < 16; ++s) tt[j][s] = sT[nloc * 17 + s];
    }
  }

  bf16*  o0 = out0 + out_off;
  float* of = outf ? outf + out_off : nullptr;
  // epilogue: C/D layout col = lane&15, row = quad*4 + r (m89-verified)
#pragma unroll
  for (int i = 0; i < 4; ++i) {
    const int mbase = m0 + wr * 64 + i * 16 + quad * 4;
#pragma unroll
    for (int r = 0; r < 4; ++r) {
      const int mm = mbase + r;
      float sv[16];
      if (EPI == EPI_ZGATE) {
        const int mloc = wr * 64 + i * 16 + quad * 4 + r;
#pragma unroll
        for (int s = 0; s < 16; ++s) sv[s] = sS[mloc * 17 + s];
      }
#pragma unroll
      for (int j = 0; j < 4; ++j) {
        const int n = n0 + wc * 64 + j * 16 + l15;
        const float bj = bias ? bias[n] : 0.f;
        float v = acc[i][j][r] + bj;
        if (EPI == EPI_SPLIT) {
          if (n < DI) o0[(size_t)mm * DI + n] = (bf16)(1.f / (1.f + __expf(-v)));
          else        out1[(size_t)mm * DI + (n - DI)] = (bf16)v;
        } else if (EPI == EPI_PLAIN) {
          o0[(size_t)mm * ldC + col_off + n] = (bf16)v;
        } else if (EPI == EPI_ZGATE) {
#pragma unroll
          for (int s = 0; s < 16; ++s) v += sv[s] * tt[j][s];
          const float g = (float)gate[(size_t)mm * DI + n];
          o0[(size_t)mm * ldC + n] = (bf16)(v * g);
        } else if (EPI == EPI_F32S) {
          of[(size_t)mm * ldC + n] = v;
        } else {  // EPI_RES: fp32 out + residual
          outf[(size_t)mm * ldC + n] = v + resid[(size_t)mm * ldC + n];
        }
      }
    }
  }
}

// ---------------------------------------------------------------------------
// RMSNorm: one block per token row (1024 fp32 -> 1024 bf16)
// ---------------------------------------------------------------------------
__global__ __launch_bounds__(256) void rmsnorm_kernel(
    const float* __restrict__ x, const float* __restrict__ w, bf16* __restrict__ out)
{
  const int row = blockIdx.x;
  const int tid = threadIdx.x;
  const float4 xv = ((const float4*)(x + (size_t)row * DMODEL))[tid];
  float s = xv.x * xv.x + xv.y * xv.y + xv.z * xv.z + xv.w * xv.w;
#pragma unroll
  for (int o = 32; o; o >>= 1) s += __shfl_xor(s, o);
  __shared__ float red[4];
  if ((tid & 63) == 0) red[tid >> 6] = s;
  __syncthreads();
  const float tot = red[0] + red[1] + red[2] + red[3];
  const float scale = rsqrtf(tot * (1.f / DMODEL) + 1e-6f);
  const float4 wv = ((const float4*)w)[tid];
  bf16x4 o4 = { (bf16)(xv.x * wv.x * scale), (bf16)(xv.y * wv.y * scale),
                (bf16)(xv.z * wv.z * scale), (bf16)(xv.w * wv.w * scale) };
  *(bf16x4*)(out + (size_t)row * DMODEL + tid * 4) = o4;
}

// ---------------------------------------------------------------------------
// 9-tap depthwise conv + silu, 4 channels/thread (bf16x4 loads). TL2=32.
// ---------------------------------------------------------------------------
static constexpr int TL2 = 32;
__global__ __launch_bounds__(256) void conv_kernel(
    const bf16* __restrict__ val,
    const float* __restrict__ sym_k, const float* __restrict__ sym_b,
    bf16* __restrict__ bbuf)
{
  const int d  = (blockIdx.y * 256 + threadIdx.x) * 4;
  const int b  = blockIdx.z;
  const int l0 = blockIdx.x * TL2;
  float wk[9][4], bs[4];
#pragma unroll
  for (int j = 0; j < 4; ++j) {
    bs[j] = sym_b[d + j];
#pragma unroll
    for (int k = 0; k < 9; ++k) wk[k][j] = sym_k[(d + j) * 9 + k];
  }
  const bf16* base = val + (size_t)b * SEQ * DI + d;

  float win[9][4];
#pragma unroll
  for (int j = 0; j < 8; ++j) {
    const int xr = l0 + j - 4;
    if (xr >= 0 && xr < SEQ) {
      bf16x4 v = *(const bf16x4*)(base + (size_t)xr * DI);
#pragma unroll
      for (int c = 0; c < 4; ++c) win[j][c] = (float)v[c];
    } else {
#pragma unroll
      for (int c = 0; c < 4; ++c) win[j][c] = 0.f;
    }
  }
  for (int t = 0; t < TL2; ++t) {
    const int xf = l0 + t + 4;
    if (xf < SEQ) {
      bf16x4 v = *(const bf16x4*)(base + (size_t)xf * DI);
#pragma unroll
      for (int c = 0; c < 4; ++c) win[8][c] = (float)v[c];
    } else {
#pragma unroll
      for (int c = 0; c < 4; ++c) win[8][c] = 0.f;
    }
    float sb[4];
#pragma unroll
    for (int c = 0; c < 4; ++c) sb[c] = bs[c];
#pragma unroll
    for (int k = 0; k < 9; ++k)
#pragma unroll
      for (int c = 0; c < 4; ++c) sb[c] += win[k][c] * wk[k][c];
    bf16x4 o;
#pragma unroll
    for (int c = 0; c < 4; ++c) o[c] = (bf16)(sb[c] / (1.f + __expf(-sb[c])));
    *(bf16x4*)(bbuf + ((size_t)b * SEQ + l0 + t) * DI + d) = o;
#pragma unroll
    for (int k = 0; k < 8; ++k)
#pragma unroll
      for (int c = 0; c < 4; ++c) win[k][c] = win[k + 1][c];
  }
}

// ---------------------------------------------------------------------------
// prep_cvt: fp32->bf16 conversions (in_w, hb_w, out_w) + pw_w transpose.
// grid = 8192 cvt blocks + 4096 transpose blocks = 12288.
// ---------------------------------------------------------------------------
__global__ __launch_bounds__(256) void prep_cvt_kernel(
    const float* __restrict__ in_w, const float* __restrict__ hb_w,
    const float* __restrict__ out_w, const float* __restrict__ pw_w,
    bf16* __restrict__ in_wbf, bf16* __restrict__ hb_bf,
    bf16* __restrict__ out_bf, bf16* __restrict__ pwT_bf)
{
  __shared__ float s[32][33];
  const int b = blockIdx.x;
  const int tid = threadIdx.x;
  if (b < 8192) {
    const float* src; bf16* dst; size_t i;
    if (b < 4096)      { src = in_w;  dst = in_wbf; i = (size_t)b * 256 + tid; }
    else if (b < 6144) { src = hb_w;  dst = hb_bf;  i = (size_t)(b - 4096) * 256 + tid; }
    else               { src = out_w; dst = out_bf; i = (size_t)(b - 6144) * 256 + tid; }
    const float4 v = ((const float4*)src)[i];
    bf16x4 o4 = { (bf16)v.x, (bf16)v.y, (bf16)v.z, (bf16)v.w };
    *(bf16x4*)(dst + 4 * i) = o4;
  } else {
    // pwT_bf[d][c] = (bf16)pw_w[c][d]
    const int q = b - 8192;
    const int d0 = (q & 63) * 32, c0 = (q >> 6) * 32;
    const int r = tid >> 5, x = tid & 31;
#pragma unroll
    for (int rr = r; rr < 32; rr += 8)
      s[rr][x] = pw_w[(size_t)(c0 + rr) * 2048 + d0 + x];
    __syncthreads();
#pragma unroll
    for (int rr = r; rr < 32; rr += 8)
      pwT_bf[(size_t)(d0 + rr) * 2048 + c0 + x] = (bf16)s[x][rr];
  }
}

// ---------------------------------------------------------------------------
// prep_small: t1 (1024) | cvec (1) | bh (4) | wprep (8) | fbcopy (2048)
//           | Ht combine (2048): Ht_bf = bf16(Hp0 + Hp1)  -> grid 5133
// ---------------------------------------------------------------------------
__global__ __launch_bounds__(256) void prep_small_kernel(
    const float* __restrict__ Bm, const float* __restrict__ ha_w,
    const float* __restrict__ dwa_b, const float* __restrict__ dwa_k,
    const float* __restrict__ A,
    const float* __restrict__ hb_w, const float* __restrict__ pw_b,
    const float* __restrict__ hb_b, const float* __restrict__ fuse_w,
    const float* __restrict__ Hp,
    float* __restrict__ T1, float* __restrict__ cvec, float* __restrict__ b_H,
    bf16* __restrict__ Wp, bf16* __restrict__ Fb, bf16* __restrict__ Ht)
{
  const int b = blockIdx.x, tid = threadIdx.x;
  __shared__ float red[4][16];
  if (b < 1024) {
    const int o = b;
    float acc[16];
#pragma unroll
    for (int s = 0; s < 16; ++s) acc[s] = 0.f;
    for (int d = tid; d < 2048; d += 256) {
      const float w = ha_w[(size_t)o * 2048 + d];
#pragma unroll
      for (int s = 0; s < 16; ++s) acc[s] += Bm[s * 2048 + d] * w;
    }
    const int lane = tid & 63, wv = tid >> 6;
#pragma unroll
    for (int s = 0; s < 16; ++s) {
      float v = acc[s];
#pragma unroll
      for (int off = 32; off; off >>= 1) v += __shfl_xor(v, off);
      if (lane == s) red[wv][s] = v;
    }
    __syncthreads();
    if (tid < 16)
      T1[tid * 1024 + o] = red[0][tid] + red[1][tid] + red[2][tid] + red[3][tid];
  } else if (b == 1024) {
    float acc[16];
#pragma unroll
    for (int s = 0; s < 16; ++s) acc[s] = 0.f;
    for (int d = tid; d < 2048; d += 256) {
      const float w = dwa_b[d];
#pragma unroll
      for (int s = 0; s < 16; ++s) acc[s] += w * A[d * 16 + s];
    }
    const int lane = tid & 63, wv = tid >> 6;
#pragma unroll
    for (int s = 0; s < 16; ++s) {
      float v = acc[s];
#pragma unroll
      for (int off = 32; off; off >>= 1) v += __shfl_xor(v, off);
      if (lane == s) red[wv][s] = v;
    }
    __syncthreads();
    if (tid < 16) cvec[tid] = red[0][tid] + red[1][tid] + red[2][tid] + red[3][tid];
  } else if (b < 1029) {
    const int o = (b - 1025) * 256 + tid;
    float acc = hb_b[o];
    const float* hr = hb_w + (size_t)o * 2048;
    for (int c = 0; c < 2048; c += 4) {
      float4 h = *(const float4*)(hr + c);
      float4 p = *(const float4*)(pw_b + c);
      acc += h.x * p.x + h.y * p.y + h.z * p.z + h.w * p.w;
    }
    b_H[o] = acc;
  } else if (b < 1037) {
    const int d = (b - 1029) * 256 + tid;
    float kk[4], av[16];
#pragma unroll
    for (int k = 0; k < 4; ++k) kk[k] = dwa_k[d * 4 + k];
#pragma unroll
    for (int s = 0; s < 16; ++s) av[s] = A[d * 16 + s];
#pragma unroll
    for (int k = 0; k < 4; ++k)
#pragma unroll
      for (int s = 0; s < 16; ++s)
        Wp[(size_t)(k * 16 + s) * 2048 + d] = (bf16)(kk[k] * av[s]);
    for (int n = 64; n < 128; ++n) Wp[(size_t)n * 2048 + d] = (bf16)0.f;
  } else if (b < 3085) {
    const int idx = (b - 1037) * 256 + tid;
    const int n = idx >> 8, o4 = idx & 255;
    float4 v = ((const float4*)(fuse_w + (size_t)n * 2048 + 1024))[o4];
    bf16x4 o = { (bf16)v.x, (bf16)v.y, (bf16)v.z, (bf16)v.w };
    *(bf16x4*)(Fb + (size_t)n * 1024 + o4 * 4) = o;
  } else {
    // Ht split-K combine: 2048 blocks x 256 threads x 1 float4
    const size_t e4 = (size_t)(b - 3085) * 256 + tid;
    float4 p0 = ((const float4*)Hp)[e4];
    float4 p1 = ((const float4*)(Hp + 2048 * 1024))[e4];
    bf16x4 o = { (bf16)(p0.x + p1.x), (bf16)(p0.y + p1.y),
                 (bf16)(p0.z + p1.z), (bf16)(p0.w + p1.w) };
    *(bf16x4*)(Ht + e4 * 4) = o;
  }
}

// ---------------------------------------------------------------------------
// prep_fuse: t2t (128 blocks) | biasz (2048 blocks, one per n). Grid 2176.
// ---------------------------------------------------------------------------
__global__ __launch_bounds__(256) void prep_fuse_kernel(
    const float* __restrict__ T1, const float* __restrict__ fuse_w,
    const float* __restrict__ fuse_b, const float* __restrict__ ha_b,
    const float* __restrict__ b_H,
    float* __restrict__ T2t, float* __restrict__ bias_z)
{
  const int b = blockIdx.x, tid = threadIdx.x;
  if (b < 128) {
    const int n = b * 16 + (tid >> 4);
    const int s = tid & 15;
    const float* fr = fuse_w + (size_t)n * 2048;
    const float* tr = T1 + s * 1024;
    float acc = 0.f;
    for (int o = 0; o < 1024; o += 4) {
      float4 f = *(const float4*)(fr + o);
      float4 t = *(const float4*)(tr + o);
      acc += f.x * t.x + f.y * t.y + f.z * t.z + f.w * t.w;
    }
    T2t[n * 16 + s] = acc;
  } else {
    const int n = b - 128;
    const float* fr = fuse_w + (size_t)n * 2048;
    const int o = tid * 4;
    float4 fa = *(const float4*)(fr + o);
    float4 fb = *(const float4*)(fr + 1024 + o);
    float4 ha = *(const float4*)(ha_b + o);
    float4 bh = *(const float4*)(b_H + o);
    float acc = fa.x * ha.x + fa.y * ha.y + fa.z * ha.z + fa.w * ha.w
              + fb.x * bh.x + fb.y * bh.y + fb.z * bh.z + fb.w * bh.w;
#pragma unroll
    for (int off = 32; off; off >>= 1) acc += __shfl_xor(acc, off);
    __shared__ float r4[4];
    if ((tid & 63) == 0) r4[tid >> 6] = acc;
    __syncthreads();
    if (tid == 0) bias_z[n] = fuse_b[n] + r4[0] + r4[1] + r4[2] + r4[3];
  }
}

// ---------------------------------------------------------------------------
// s16_kernel: s16[m,s] = cvec[s] + sum_k (P0+P1)[bb, l-1+k, k*16+s]
// grid = MTOK*16/256 = 1024 blocks. 1 MB fp32 output (replaces 64MB z_a).
// ---------------------------------------------------------------------------
__global__ __launch_bounds__(256) void s16_kernel(
    const bf16* __restrict__ P0, const bf16* __restrict__ P1,
    const float* __restrict__ cvec, float* __restrict__ s16f)
{
  const int g = blockIdx.x * 256 + threadIdx.x;
  const int tok = g >> 4, s = g & 15;
  const int l = tok & (SEQ - 1), bb = tok >> 12;
  float acc = cvec[s];
#pragma unroll
  for (int k = 0; k < 4; ++k) {
    const int r = l - 1 + k;
    if ((unsigned)r < (unsigned)SEQ) {
      const size_t idx = ((size_t)bb * SEQ + r) * 128 + k * 16 + s;
      acc += (float)P0[idx] + (float)P1[idx];
    }
  }
  s16f[(size_t)tok * 16 + s] = acc;
}

// ---------------------------------------------------------------------------
extern "C" void kernel_launch(void* const* d_in, const int* in_sizes, int n_in,
                              void* d_out, int out_size, void* d_ws, size_t ws_size,
                              hipStream_t stream)
{
  const float* x      = (const float*)d_in[0];
  const float* norm_w = (const float*)d_in[1];
  const float* in_w   = (const float*)d_in[2];
  const float* in_b   = (const float*)d_in[3];
  const float* dwa_k  = (const float*)d_in[4];
  const float* dwa_b  = (const float*)d_in[5];
  const float* Amat   = (const float*)d_in[6];
  const float* Bm     = (const float*)d_in[7];
  const float* sym_k  = (const float*)d_in[8];
  const float* sym_b  = (const float*)d_in[9];
  const float* pw_w   = (const float*)d_in[10];
  const float* pw_b   = (const float*)d_in[11];
  const float* ha_w   = (const float*)d_in[12];
  const float* ha_b   = (const float*)d_in[13];
  const float* hb_w   = (const float*)d_in[14];
  const float* hb_b   = (const float*)d_in[15];
  const float* fuse_w = (const float*)d_in[16];
  const float* fuse_b = (const float*)d_in[17];
  const float* out_w  = (const float*)d_in[18];
  const float* out_b  = (const float*)d_in[19];
  float* out = (float*)d_out;

  char* ws = (char*)d_ws;
  const size_t MB = 1u << 20, KB = 1u << 10;
  // Overlay plan (peak ~220.8 MB):
  //  R0 [0,64):   in_wbf[0,8) + hnorm[8,40)  ->  bsilu
  //  R1 [64,128): Hpart (prep, 16 MB)  ->  val  ->  y2 (zbuf, write-only)
  //  R2 [128,192): gate
  //  s16f overlays Fb_bf (dead after WB-GEMM).
  bf16*  in_wbf  = (bf16*)(ws + 0);
  bf16*  hnorm   = (bf16*)(ws + 8 * MB);
  bf16*  bsilu   = (bf16*)(ws + 0);
  float* Hpart   = (float*)(ws + 64 * MB);              // 16 MB, prep-only
  bf16*  valp    = (bf16*)(ws + 64 * MB);
  bf16*  zbuf    = (bf16*)(ws + 64 * MB);
  bf16*  gatep   = (bf16*)(ws + 128 * MB);
  bf16*  Pbuf    = (bf16*)(ws + 192 * MB);              // 8 MB (2 split-K parts)
  bf16*  pwT_bf  = (bf16*)(ws + 200 * MB);              // 8 MB (dead after Ht)
  bf16*  WB_bf   = (bf16*)(ws + 200 * MB);              // 8 MB (overlays pwT)
  bf16*  hb_bf   = (bf16*)(ws + 208 * MB);              // 4 MB (dead after Ht)
  bf16*  Fb_bf   = (bf16*)(ws + 208 * MB);              // 4 MB (dead after WB)
  float* s16f    = (float*)(ws + 208 * MB);             // 1 MB (overlays Fb)
  bf16*  Ht_bf   = (bf16*)(ws + 212 * MB);              // 4 MB
  bf16*  out_bf  = (bf16*)(ws + 216 * MB);              // 4 MB
  float* T1      = (float*)(ws + 220 * MB);             // 64 KB
  float* cvec    = (float*)(ws + 220 * MB + 64 * KB);   // 64 B
  float* b_H     = (float*)(ws + 220 * MB + 68 * KB);   // 4 KB
  float* bias_z  = (float*)(ws + 220 * MB + 72 * KB);   // 8 KB
  bf16*  Wp      = (bf16*)(ws + 220 * MB + 80 * KB);    // 512 KB
  float* T2t     = (float*)(ws + 220 * MB + 592 * KB);  // 128 KB -> 220.70 MB

  // ---- weight prep (5 launches) ----
  prep_cvt_kernel<<<12288, 256, 0, stream>>>(
      in_w, hb_w, out_w, pw_w, in_wbf, hb_bf, out_bf, pwT_bf);
  // Ht[d,o] = sum_c pw_w[c,d]*hb_w[o,c] — split-K=2, fp32 partials -> Hpart
  gemm_bt<EPI_F32S, true><<<dim3(2, 16, 8), 256, 0, stream>>>(
      pwT_bf, hb_bf, nullptr, nullptr, nullptr, nullptr, Hpart, nullptr,
      1024, 2048, 1024, 2048 * 1024);
  prep_small_kernel<<<5133, 256, 0, stream>>>(
      Bm, ha_w, dwa_b, dwa_k, Amat, hb_w, pw_b, hb_b, fuse_w, Hpart,
      T1, cvec, b_H, Wp, Fb_bf, Ht_bf);
  // W_B[n,d] = sum_o F_b[n,o]*Ht[d,o]  (= F_b@hb_w@pw_w)
  gemm_bt<EPI_PLAIN><<<dim3(16, 16), 256, 0, stream>>>(
      Fb_bf, Ht_bf, nullptr, WB_bf, nullptr, nullptr, nullptr, nullptr, 2048, 1024, 2048, 0);
  prep_fuse_kernel<<<2176, 256, 0, stream>>>(T1, fuse_w, fuse_b, ha_b, b_H, T2t, bias_z);

  // ---- main chain (7 launches) ----
  rmsnorm_kernel<<<MTOK, 256, 0, stream>>>(x, norm_w, hnorm);
  // in-proj: gate = sigmoid(h[:, :DI]), val = h[:, DI:]
  gemm_bt<EPI_SPLIT><<<dim3(32, 128), 256, 0, stream>>>(
      hnorm, in_wbf, in_b, gatep, valp, nullptr, nullptr, nullptr, 4096, 1024, DI, 0);
  // 9-tap conv + silu (val -> bsilu, overlays dead in_wbf/hnorm)
  conv_kernel<<<dim3(SEQ / TL2, 2, BATCH), 256, 0, stream>>>(
      valp, sym_k, sym_b, bsilu);
  // skinny P GEMM, split-K=2: P = val @ Wp^T  (N=128 padded)
  gemm_bt<EPI_PLAIN, true><<<dim3(2, 128), 256, 0, stream>>>(
      valp, Wp, nullptr, Pbuf, nullptr, nullptr, nullptr, nullptr, 128, 2048, 128, 0);
  // s16 = windowed P-sum + cvec (1 MB; replaces 64MB z_a materialization)
  s16_kernel<<<MTOK * 16 / 256, 256, 0, stream>>>(
      Pbuf, Pbuf + (size_t)MTOK * 128, cvec, s16f);
  // B-GEMM, fused rank-16 z_a + gate epilogue (zbuf write-only now):
  // y2 = gate * (bsilu @ W_B^T + bias_z + s16 @ T2t^T)
  gemm_bt<EPI_ZGATE><<<dim3(16, 128), 256, 0, stream>>>(
      bsilu, WB_bf, bias_z, zbuf, nullptr, gatep, s16f, T2t, 2048, 2048, 2048, 0);
  // out GEMM + residual -> fp32 d_out
  gemm_bt<EPI_RES><<<dim3(8, 128), 256, 0, stream>>>(
      zbuf, out_bf, out_b, nullptr, nullptr, nullptr, out, x, 1024, 2048, 1024, 0);
}

// Round 7
// 836.705 us; speedup vs baseline: 1.1351x; 1.1351x over previous
//
#include <hip/hip_runtime.h>
#include <hip/hip_bf16.h>
#include <stdint.h>

typedef __bf16 bf16;
typedef __bf16 bf16x8 __attribute__((ext_vector_type(8)));
typedef __bf16 bf16x4 __attribute__((ext_vector_type(4)));
typedef float  f32x4  __attribute__((ext_vector_type(4)));

#define LDS_PTR(p) ((__attribute__((address_space(3))) uint32_t*)(p))
#define GLB_PTR(p) ((const __attribute__((address_space(1))) uint32_t*)(p))

static constexpr int BATCH = 4, SEQ = 4096, DMODEL = 1024;
static constexpr int DI = 2048;
static constexpr int MTOK = BATCH * SEQ;   // 16384 tokens

enum { EPI_SPLIT = 0, EPI_PLAIN = 1, EPI_GATE = 2, EPI_RES = 3, EPI_F32S = 4 };

// ---------------------------------------------------------------------------
// 128x128-tile bf16 GEMM (m97 structure) — the proven workhorse (~780 TF).
// SPLITK: blockIdx.x = K-split, blockIdx.y = m-tile, blockIdx.z = n-tile.
// KEXT: one extra K-tile staged from side buffers Ax[M][64] / Bx[N][64]
//   (bf16, cols>=16 zeroed) — folds the rank-16 z_a correction into the
//   MFMA K-loop at zero register/occupancy cost (round-6 lesson: epilogue
//   fusion cost VGPR 80->116, occupancy 28->21, -50us).
// EPI_GATE: y2 = gate * (acc + bias[n]); out write-only.
// ---------------------------------------------------------------------------
template <int EPI, bool SPLITK = false, bool KEXT = false>
__global__ __launch_bounds__(256) void gemm_bt(
    const bf16* __restrict__ Aact, const bf16* __restrict__ W,
    const float* __restrict__ bias,
    bf16* __restrict__ out0, bf16* __restrict__ out1,
    const bf16* __restrict__ gate,
    float* __restrict__ outf, const float* __restrict__ resid,
    int N, int K, int ldC, int col_off,
    const bf16* __restrict__ Ax, const bf16* __restrict__ Bx)
{
  __shared__ __align__(16) bf16 sA[128 * 64];
  __shared__ __align__(16) bf16 sB[128 * 64];
  const int tid  = threadIdx.x;
  int n0, m0, kbeg, kend;
  size_t out_off = 0;
  if (SPLITK) {
    n0 = blockIdx.z * 128;
    m0 = blockIdx.y * 128;
    const int kh = K / gridDim.x;
    kbeg = blockIdx.x * kh; kend = kbeg + kh;
    out_off = (EPI == EPI_F32S) ? (size_t)blockIdx.x * (size_t)col_off
                                : (size_t)blockIdx.x * ((size_t)MTOK * 128);
  } else {
    const int nT  = gridDim.x;
    const int lin = blockIdx.y * nT + blockIdx.x;
    const int grp = lin / (8 * nT);
    const int within = lin - grp * (8 * nT);
    n0 = (within >> 3) * 128;
    m0 = (grp * 8 + (within & 7)) * 128;
    kbeg = 0; kend = K;
  }
  const int lane = tid & 63;
  const int wv   = tid >> 6;
  const int wr   = wv >> 1, wc = wv & 1;
  const int l15  = lane & 15, quad = lane >> 4;

  f32x4 acc[4][4];
#pragma unroll
  for (int i = 0; i < 4; ++i)
#pragma unroll
    for (int j = 0; j < 4; ++j) acc[i][j] = (f32x4){0.f, 0.f, 0.f, 0.f};

  int rr[4], cb[4];
#pragma unroll
  for (int j = 0; j < 4; ++j) {
    const int s = tid + j * 256;
    rr[j] = s >> 3;
    cb[j] = ((s & 7) ^ (rr[j] & 7)) * 16;
  }

  const char* gA = (const char*)(Aact + (size_t)m0 * K);
  const char* gW = (const char*)(W + (size_t)n0 * K);

  const int ntile = (kend - kbeg) >> 6;
  const int ttot  = KEXT ? ntile + 1 : ntile;
  for (int ti = 0; ti < ttot; ++ti) {
    if (ti) __syncthreads();
    if (!KEXT || ti < ntile) {
      const int k0 = kbeg + ti * 64;
#pragma unroll
      for (int j = 0; j < 4; ++j)
        __builtin_amdgcn_global_load_lds(GLB_PTR(gA + ((size_t)rr[j] * K + k0) * 2 + cb[j]),
                                         LDS_PTR(sA + (tid + j * 256) * 8), 16, 0, 0);
#pragma unroll
      for (int j = 0; j < 4; ++j)
        __builtin_amdgcn_global_load_lds(GLB_PTR(gW + ((size_t)rr[j] * K + k0) * 2 + cb[j]),
                                         LDS_PTR(sB + (tid + j * 256) * 8), 16, 0, 0);
    } else {
      // rank-16 extension tile: rows of Ax/Bx are 64 bf16 = 128 B (same
      // geometry as one K-tile row), cols 16..63 are zero.
#pragma unroll
      for (int j = 0; j < 4; ++j)
        __builtin_amdgcn_global_load_lds(GLB_PTR((const char*)Ax + ((size_t)(m0 + rr[j]) * 64) * 2 + cb[j]),
                                         LDS_PTR(sA + (tid + j * 256) * 8), 16, 0, 0);
#pragma unroll
      for (int j = 0; j < 4; ++j)
        __builtin_amdgcn_global_load_lds(GLB_PTR((const char*)Bx + ((size_t)(n0 + rr[j]) * 64) * 2 + cb[j]),
                                         LDS_PTR(sB + (tid + j * 256) * 8), 16, 0, 0);
    }
    __syncthreads();

#pragma unroll
    for (int h = 0; h < 2; ++h) {
      bf16x8 av[4], bv[4];
#pragma unroll
      for (int t = 0; t < 4; ++t) {
        const int Ra = wr * 64 + t * 16 + l15;
        const int Rb = wc * 64 + t * 16 + l15;
        const int cc = h * 4 + quad;
        av[t] = *(const bf16x8*)(sA + (Ra * 8 + (cc ^ (Ra & 7))) * 8);
        bv[t] = *(const bf16x8*)(sB + (Rb * 8 + (cc ^ (Rb & 7))) * 8);
      }
#pragma unroll
      for (int i = 0; i < 4; ++i)
#pragma unroll
        for (int j = 0; j < 4; ++j)
          acc[i][j] = __builtin_amdgcn_mfma_f32_16x16x32_bf16(av[i], bv[j], acc[i][j], 0, 0, 0);
    }
  }

  bf16*  o0 = out0 + out_off;
  float* of = outf ? outf + out_off : nullptr;
  // epilogue: C/D layout col = lane&15, row = quad*4 + r (m89-verified)
#pragma unroll
  for (int i = 0; i < 4; ++i) {
    const int mbase = m0 + wr * 64 + i * 16 + quad * 4;
#pragma unroll
    for (int j = 0; j < 4; ++j) {
      const int n = n0 + wc * 64 + j * 16 + l15;
      const float bj = bias ? bias[n] : 0.f;
#pragma unroll
      for (int r = 0; r < 4; ++r) {
        const int mm = mbase + r;
        float v = acc[i][j][r] + bj;
        if (EPI == EPI_SPLIT) {
          if (n < DI) o0[(size_t)mm * DI + n] = (bf16)(1.f / (1.f + __expf(-v)));
          else        out1[(size_t)mm * DI + (n - DI)] = (bf16)v;
        } else if (EPI == EPI_PLAIN) {
          o0[(size_t)mm * ldC + col_off + n] = (bf16)v;
        } else if (EPI == EPI_GATE) {
          const float g = (float)gate[(size_t)mm * DI + n];
          o0[(size_t)mm * ldC + n] = (bf16)(v * g);
        } else if (EPI == EPI_F32S) {
          of[(size_t)mm * ldC + n] = v;
        } else {  // EPI_RES: fp32 out + residual
          outf[(size_t)mm * ldC + n] = v + resid[(size_t)mm * ldC + n];
        }
      }
    }
  }
}

// ---------------------------------------------------------------------------
// RMSNorm: one block per token row (1024 fp32 -> 1024 bf16)
// ---------------------------------------------------------------------------
__global__ __launch_bounds__(256) void rmsnorm_kernel(
    const float* __restrict__ x, const float* __restrict__ w, bf16* __restrict__ out)
{
  const int row = blockIdx.x;
  const int tid = threadIdx.x;
  const float4 xv = ((const float4*)(x + (size_t)row * DMODEL))[tid];
  float s = xv.x * xv.x + xv.y * xv.y + xv.z * xv.z + xv.w * xv.w;
#pragma unroll
  for (int o = 32; o; o >>= 1) s += __shfl_xor(s, o);
  __shared__ float red[4];
  if ((tid & 63) == 0) red[tid >> 6] = s;
  __syncthreads();
  const float tot = red[0] + red[1] + red[2] + red[3];
  const float scale = rsqrtf(tot * (1.f / DMODEL) + 1e-6f);
  const float4 wv = ((const float4*)w)[tid];
  bf16x4 o4 = { (bf16)(xv.x * wv.x * scale), (bf16)(xv.y * wv.y * scale),
                (bf16)(xv.z * wv.z * scale), (bf16)(xv.w * wv.w * scale) };
  *(bf16x4*)(out + (size_t)row * DMODEL + tid * 4) = o4;
}

// ---------------------------------------------------------------------------
// 9-tap depthwise conv + silu, 4 channels/thread (bf16x4 loads). TL2=32.
// ---------------------------------------------------------------------------
static constexpr int TL2 = 32;
__global__ __launch_bounds__(256) void conv_kernel(
    const bf16* __restrict__ val,
    const float* __restrict__ sym_k, const float* __restrict__ sym_b,
    bf16* __restrict__ bbuf)
{
  const int d  = (blockIdx.y * 256 + threadIdx.x) * 4;
  const int b  = blockIdx.z;
  const int l0 = blockIdx.x * TL2;
  float wk[9][4], bs[4];
#pragma unroll
  for (int j = 0; j < 4; ++j) {
    bs[j] = sym_b[d + j];
#pragma unroll
    for (int k = 0; k < 9; ++k) wk[k][j] = sym_k[(d + j) * 9 + k];
  }
  const bf16* base = val + (size_t)b * SEQ * DI + d;

  float win[9][4];
#pragma unroll
  for (int j = 0; j < 8; ++j) {
    const int xr = l0 + j - 4;
    if (xr >= 0 && xr < SEQ) {
      bf16x4 v = *(const bf16x4*)(base + (size_t)xr * DI);
#pragma unroll
      for (int c = 0; c < 4; ++c) win[j][c] = (float)v[c];
    } else {
#pragma unroll
      for (int c = 0; c < 4; ++c) win[j][c] = 0.f;
    }
  }
  for (int t = 0; t < TL2; ++t) {
    const int xf = l0 + t + 4;
    if (xf < SEQ) {
      bf16x4 v = *(const bf16x4*)(base + (size_t)xf * DI);
#pragma unroll
      for (int c = 0; c < 4; ++c) win[8][c] = (float)v[c];
    } else {
#pragma unroll
      for (int c = 0; c < 4; ++c) win[8][c] = 0.f;
    }
    float sb[4];
#pragma unroll
    for (int c = 0; c < 4; ++c) sb[c] = bs[c];
#pragma unroll
    for (int k = 0; k < 9; ++k)
#pragma unroll
      for (int c = 0; c < 4; ++c) sb[c] += win[k][c] * wk[k][c];
    bf16x4 o;
#pragma unroll
    for (int c = 0; c < 4; ++c) o[c] = (bf16)(sb[c] / (1.f + __expf(-sb[c])));
    *(bf16x4*)(bbuf + ((size_t)b * SEQ + l0 + t) * DI + d) = o;
#pragma unroll
    for (int k = 0; k < 8; ++k)
#pragma unroll
      for (int c = 0; c < 4; ++c) win[k][c] = win[k + 1][c];
  }
}

// ---------------------------------------------------------------------------
// prep_cvt: fp32->bf16 conversions (in_w, hb_w, out_w) + pw_w transpose.
// ---------------------------------------------------------------------------
__global__ __launch_bounds__(256) void prep_cvt_kernel(
    const float* __restrict__ in_w, const float* __restrict__ hb_w,
    const float* __restrict__ out_w, const float* __restrict__ pw_w,
    bf16* __restrict__ in_wbf, bf16* __restrict__ hb_bf,
    bf16* __restrict__ out_bf, bf16* __restrict__ pwT_bf)
{
  __shared__ float s[32][33];
  const int b = blockIdx.x;
  const int tid = threadIdx.x;
  if (b < 8192) {
    const float* src; bf16* dst; size_t i;
    if (b < 4096)      { src = in_w;  dst = in_wbf; i = (size_t)b * 256 + tid; }
    else if (b < 6144) { src = hb_w;  dst = hb_bf;  i = (size_t)(b - 4096) * 256 + tid; }
    else               { src = out_w; dst = out_bf; i = (size_t)(b - 6144) * 256 + tid; }
    const float4 v = ((const float4*)src)[i];
    bf16x4 o4 = { (bf16)v.x, (bf16)v.y, (bf16)v.z, (bf16)v.w };
    *(bf16x4*)(dst + 4 * i) = o4;
  } else {
    const int q = b - 8192;
    const int d0 = (q & 63) * 32, c0 = (q >> 6) * 32;
    const int r = tid >> 5, x = tid & 31;
#pragma unroll
    for (int rr = r; rr < 32; rr += 8)
      s[rr][x] = pw_w[(size_t)(c0 + rr) * 2048 + d0 + x];
    __syncthreads();
#pragma unroll
    for (int rr = r; rr < 32; rr += 8)
      pwT_bf[(size_t)(d0 + rr) * 2048 + c0 + x] = (bf16)s[x][rr];
  }
}

// ---------------------------------------------------------------------------
// prep_small: t1 (1024) | cvec (1) | bh (4) | wprep (8) | fbcopy (2048)
//           | Ht combine (2048): Ht_bf = bf16(Hp0 + Hp1)  -> grid 5133
// ---------------------------------------------------------------------------
__global__ __launch_bounds__(256) void prep_small_kernel(
    const float* __restrict__ Bm, const float* __restrict__ ha_w,
    const float* __restrict__ dwa_b, const float* __restrict__ dwa_k,
    const float* __restrict__ A,
    const float* __restrict__ hb_w, const float* __restrict__ pw_b,
    const float* __restrict__ hb_b, const float* __restrict__ fuse_w,
    const float* __restrict__ Hp,
    float* __restrict__ T1, float* __restrict__ cvec, float* __restrict__ b_H,
    bf16* __restrict__ Wp, bf16* __restrict__ Fb, bf16* __restrict__ Ht)
{
  const int b = blockIdx.x, tid = threadIdx.x;
  __shared__ float red[4][16];
  if (b < 1024) {
    const int o = b;
    float acc[16];
#pragma unroll
    for (int s = 0; s < 16; ++s) acc[s] = 0.f;
    for (int d = tid; d < 2048; d += 256) {
      const float w = ha_w[(size_t)o * 2048 + d];
#pragma unroll
      for (int s = 0; s < 16; ++s) acc[s] += Bm[s * 2048 + d] * w;
    }
    const int lane = tid & 63, wv = tid >> 6;
#pragma unroll
    for (int s = 0; s < 16; ++s) {
      float v = acc[s];
#pragma unroll
      for (int off = 32; off; off >>= 1) v += __shfl_xor(v, off);
      if (lane == s) red[wv][s] = v;
    }
    __syncthreads();
    if (tid < 16)
      T1[tid * 1024 + o] = red[0][tid] + red[1][tid] + red[2][tid] + red[3][tid];
  } else if (b == 1024) {
    float acc[16];
#pragma unroll
    for (int s = 0; s < 16; ++s) acc[s] = 0.f;
    for (int d = tid; d < 2048; d += 256) {
      const float w = dwa_b[d];
#pragma unroll
      for (int s = 0; s < 16; ++s) acc[s] += w * A[d * 16 + s];
    }
    const int lane = tid & 63, wv = tid >> 6;
#pragma unroll
    for (int s = 0; s < 16; ++s) {
      float v = acc[s];
#pragma unroll
      for (int off = 32; off; off >>= 1) v += __shfl_xor(v, off);
      if (lane == s) red[wv][s] = v;
    }
    __syncthreads();
    if (tid < 16) cvec[tid] = red[0][tid] + red[1][tid] + red[2][tid] + red[3][tid];
  } else if (b < 1029) {
    const int o = (b - 1025) * 256 + tid;
    float acc = hb_b[o];
    const float* hr = hb_w + (size_t)o * 2048;
    for (int c = 0; c < 2048; c += 4) {
      float4 h = *(const float4*)(hr + c);
      float4 p = *(const float4*)(pw_b + c);
      acc += h.x * p.x + h.y * p.y + h.z * p.z + h.w * p.w;
    }
    b_H[o] = acc;
  } else if (b < 1037) {
    const int d = (b - 1029) * 256 + tid;
    float kk[4], av[16];
#pragma unroll
    for (int k = 0; k < 4; ++k) kk[k] = dwa_k[d * 4 + k];
#pragma unroll
    for (int s = 0; s < 16; ++s) av[s] = A[d * 16 + s];
#pragma unroll
    for (int k = 0; k < 4; ++k)
#pragma unroll
      for (int s = 0; s < 16; ++s)
        Wp[(size_t)(k * 16 + s) * 2048 + d] = (bf16)(kk[k] * av[s]);
    for (int n = 64; n < 128; ++n) Wp[(size_t)n * 2048 + d] = (bf16)0.f;
  } else if (b < 3085) {
    const int idx = (b - 1037) * 256 + tid;
    const int n = idx >> 8, o4 = idx & 255;
    float4 v = ((const float4*)(fuse_w + (size_t)n * 2048 + 1024))[o4];
    bf16x4 o = { (bf16)v.x, (bf16)v.y, (bf16)v.z, (bf16)v.w };
    *(bf16x4*)(Fb + (size_t)n * 1024 + o4 * 4) = o;
  } else {
    // Ht split-K combine: 2048 blocks x 256 threads x 1 float4
    const size_t e4 = (size_t)(b - 3085) * 256 + tid;
    float4 p0 = ((const float4*)Hp)[e4];
    float4 p1 = ((const float4*)(Hp + 2048 * 1024))[e4];
    bf16x4 o = { (bf16)(p0.x + p1.x), (bf16)(p0.y + p1.y),
                 (bf16)(p0.z + p1.z), (bf16)(p0.w + p1.w) };
    *(bf16x4*)(Ht + e4 * 4) = o;
  }
}

// ---------------------------------------------------------------------------
// prep_fuse: t2t (128 blocks, writes T2e[2048][64] bf16 ext-tile layout)
//          | biasz (2048 blocks, one per n). Grid 2176.
// ---------------------------------------------------------------------------
__global__ __launch_bounds__(256) void prep_fuse_kernel(
    const float* __restrict__ T1, const float* __restrict__ fuse_w,
    const float* __restrict__ fuse_b, const float* __restrict__ ha_b,
    const float* __restrict__ b_H,
    bf16* __restrict__ T2e, float* __restrict__ bias_z)
{
  const int b = blockIdx.x, tid = threadIdx.x;
  if (b < 128) {
    const int n = b * 16 + (tid >> 4);
    const int s = tid & 15;
    const float* fr = fuse_w + (size_t)n * 2048;
    const float* tr = T1 + s * 1024;
    float acc = 0.f;
    for (int o = 0; o < 1024; o += 4) {
      float4 f = *(const float4*)(fr + o);
      float4 t = *(const float4*)(tr + o);
      acc += f.x * t.x + f.y * t.y + f.z * t.z + f.w * t.w;
    }
    T2e[(size_t)n * 64 + s]      = (bf16)acc;
    T2e[(size_t)n * 64 + s + 16] = (bf16)0.f;
    T2e[(size_t)n * 64 + s + 32] = (bf16)0.f;
    T2e[(size_t)n * 64 + s + 48] = (bf16)0.f;
  } else {
    const int n = b - 128;
    const float* fr = fuse_w + (size_t)n * 2048;
    const int o = tid * 4;
    float4 fa = *(const float4*)(fr + o);
    float4 fb = *(const float4*)(fr + 1024 + o);
    float4 ha = *(const float4*)(ha_b + o);
    float4 bh = *(const float4*)(b_H + o);
    float acc = fa.x * ha.x + fa.y * ha.y + fa.z * ha.z + fa.w * ha.w
              + fb.x * bh.x + fb.y * bh.y + fb.z * bh.z + fb.w * bh.w;
#pragma unroll
    for (int off = 32; off; off >>= 1) acc += __shfl_xor(acc, off);
    __shared__ float r4[4];
    if ((tid & 63) == 0) r4[tid >> 6] = acc;
    __syncthreads();
    if (tid == 0) bias_z[n] = fuse_b[n] + r4[0] + r4[1] + r4[2] + r4[3];
  }
}

// ---------------------------------------------------------------------------
// s16_kernel: s16e[tok][s] = cvec[s] + sum_k (P0+P1)[bb, l-1+k, k*16+s]
// bf16 ext-tile layout [MTOK][64], cols 16..63 zero. 2 MB (vs 64 MB z_a).
// ---------------------------------------------------------------------------
__global__ __launch_bounds__(256) void s16_kernel(
    const bf16* __restrict__ P0, const bf16* __restrict__ P1,
    const float* __restrict__ cvec, bf16* __restrict__ s16e)
{
  const int g = blockIdx.x * 256 + threadIdx.x;
  const int tok = g >> 4, s = g & 15;
  const int l = tok & (SEQ - 1), bb = tok >> 12;
  float acc = cvec[s];
#pragma unroll
  for (int k = 0; k < 4; ++k) {
    const int r = l - 1 + k;
    if ((unsigned)r < (unsigned)SEQ) {
      const size_t idx = ((size_t)bb * SEQ + r) * 128 + k * 16 + s;
      acc += (float)P0[idx] + (float)P1[idx];
    }
  }
  s16e[(size_t)tok * 64 + s]      = (bf16)acc;
  s16e[(size_t)tok * 64 + s + 16] = (bf16)0.f;
  s16e[(size_t)tok * 64 + s + 32] = (bf16)0.f;
  s16e[(size_t)tok * 64 + s + 48] = (bf16)0.f;
}

// ---------------------------------------------------------------------------
extern "C" void kernel_launch(void* const* d_in, const int* in_sizes, int n_in,
                              void* d_out, int out_size, void* d_ws, size_t ws_size,
                              hipStream_t stream)
{
  const float* x      = (const float*)d_in[0];
  const float* norm_w = (const float*)d_in[1];
  const float* in_w   = (const float*)d_in[2];
  const float* in_b   = (const float*)d_in[3];
  const float* dwa_k  = (const float*)d_in[4];
  const float* dwa_b  = (const float*)d_in[5];
  const float* Amat   = (const float*)d_in[6];
  const float* Bm     = (const float*)d_in[7];
  const float* sym_k  = (const float*)d_in[8];
  const float* sym_b  = (const float*)d_in[9];
  const float* pw_w   = (const float*)d_in[10];
  const float* pw_b   = (const float*)d_in[11];
  const float* ha_w   = (const float*)d_in[12];
  const float* ha_b   = (const float*)d_in[13];
  const float* hb_w   = (const float*)d_in[14];
  const float* hb_b   = (const float*)d_in[15];
  const float* fuse_w = (const float*)d_in[16];
  const float* fuse_b = (const float*)d_in[17];
  const float* out_w  = (const float*)d_in[18];
  const float* out_b  = (const float*)d_in[19];
  float* out = (float*)d_out;

  char* ws = (char*)d_ws;
  const size_t MB = 1u << 20, KB = 1u << 10;
  // Overlay plan (peak ~220.9 MB):
  //  R0 [0,64):   in_wbf[0,8) + hnorm[8,40)  ->  bsilu
  //  R1 [64,128): Hpart (prep, 16 MB)  ->  val  ->  y2 (zbuf, write-only)
  //  R2 [128,192): gate
  //  s16e (2 MB) overlays Fb_bf (dead after WB-GEMM).
  bf16*  in_wbf  = (bf16*)(ws + 0);
  bf16*  hnorm   = (bf16*)(ws + 8 * MB);
  bf16*  bsilu   = (bf16*)(ws + 0);
  float* Hpart   = (float*)(ws + 64 * MB);              // 16 MB, prep-only
  bf16*  valp    = (bf16*)(ws + 64 * MB);
  bf16*  zbuf    = (bf16*)(ws + 64 * MB);
  bf16*  gatep   = (bf16*)(ws + 128 * MB);
  bf16*  Pbuf    = (bf16*)(ws + 192 * MB);              // 8 MB (2 split-K parts)
  bf16*  pwT_bf  = (bf16*)(ws + 200 * MB);              // 8 MB (dead after Ht)
  bf16*  WB_bf   = (bf16*)(ws + 200 * MB);              // 8 MB (overlays pwT)
  bf16*  hb_bf   = (bf16*)(ws + 208 * MB);              // 4 MB (dead after Ht)
  bf16*  Fb_bf   = (bf16*)(ws + 208 * MB);              // 4 MB (dead after WB)
  bf16*  s16e    = (bf16*)(ws + 208 * MB);              // 2 MB (overlays Fb)
  bf16*  Ht_bf   = (bf16*)(ws + 212 * MB);              // 4 MB
  bf16*  out_bf  = (bf16*)(ws + 216 * MB);              // 4 MB
  float* T1      = (float*)(ws + 220 * MB);             // 64 KB
  float* cvec    = (float*)(ws + 220 * MB + 64 * KB);   // 64 B
  float* b_H     = (float*)(ws + 220 * MB + 68 * KB);   // 4 KB
  float* bias_z  = (float*)(ws + 220 * MB + 72 * KB);   // 8 KB
  bf16*  Wp      = (bf16*)(ws + 220 * MB + 80 * KB);    // 512 KB
  bf16*  T2e     = (bf16*)(ws + 220 * MB + 592 * KB);   // 256 KB -> 220.83 MB

  // ---- weight prep (5 launches) ----
  prep_cvt_kernel<<<12288, 256, 0, stream>>>(
      in_w, hb_w, out_w, pw_w, in_wbf, hb_bf, out_bf, pwT_bf);
  // Ht[d,o] = sum_c pw_w[c,d]*hb_w[o,c] — split-K=2, fp32 partials -> Hpart
  gemm_bt<EPI_F32S, true><<<dim3(2, 16, 8), 256, 0, stream>>>(
      pwT_bf, hb_bf, nullptr, nullptr, nullptr, nullptr, Hpart, nullptr,
      1024, 2048, 1024, 2048 * 1024, nullptr, nullptr);
  prep_small_kernel<<<5133, 256, 0, stream>>>(
      Bm, ha_w, dwa_b, dwa_k, Amat, hb_w, pw_b, hb_b, fuse_w, Hpart,
      T1, cvec, b_H, Wp, Fb_bf, Ht_bf);
  // W_B[n,d] = sum_o F_b[n,o]*Ht[d,o]  (= F_b@hb_w@pw_w)
  gemm_bt<EPI_PLAIN><<<dim3(16, 16), 256, 0, stream>>>(
      Fb_bf, Ht_bf, nullptr, WB_bf, nullptr, nullptr, nullptr, nullptr,
      2048, 1024, 2048, 0, nullptr, nullptr);
  prep_fuse_kernel<<<2176, 256, 0, stream>>>(T1, fuse_w, fuse_b, ha_b, b_H, T2e, bias_z);

  // ---- main chain (7 launches) ----
  rmsnorm_kernel<<<MTOK, 256, 0, stream>>>(x, norm_w, hnorm);
  // in-proj: gate = sigmoid(h[:, :DI]), val = h[:, DI:]
  gemm_bt<EPI_SPLIT><<<dim3(32, 128), 256, 0, stream>>>(
      hnorm, in_wbf, in_b, gatep, valp, nullptr, nullptr, nullptr,
      4096, 1024, DI, 0, nullptr, nullptr);
  // 9-tap conv + silu (val -> bsilu, overlays dead in_wbf/hnorm)
  conv_kernel<<<dim3(SEQ / TL2, 2, BATCH), 256, 0, stream>>>(
      valp, sym_k, sym_b, bsilu);
  // skinny P GEMM, split-K=2: P = val @ Wp^T  (N=128 padded)
  gemm_bt<EPI_PLAIN, true><<<dim3(2, 128), 256, 0, stream>>>(
      valp, Wp, nullptr, Pbuf, nullptr, nullptr, nullptr, nullptr,
      128, 2048, 128, 0, nullptr, nullptr);
  // s16 ext tile (2 MB; replaces 64 MB z_a materialization)
  s16_kernel<<<MTOK * 16 / 256, 256, 0, stream>>>(
      Pbuf, Pbuf + (size_t)MTOK * 128, cvec, s16e);
  // B-GEMM with rank-16 K-extension: y2 = gate*(bsilu@W_B^T + s16@T2t^T + bias_z)
  gemm_bt<EPI_GATE, false, true><<<dim3(16, 128), 256, 0, stream>>>(
      bsilu, WB_bf, bias_z, zbuf, nullptr, gatep, nullptr, nullptr,
      2048, 2048, 2048, 0, s16e, T2e);
  // out GEMM + residual -> fp32 d_out
  gemm_bt<EPI_RES><<<dim3(8, 128), 256, 0, stream>>>(
      zbuf, out_bf, out_b, nullptr, nullptr, nullptr, out, x,
      1024, 2048, 1024, 0, nullptr, nullptr);
}

// Round 8
// 806.284 us; speedup vs baseline: 1.1780x; 1.0377x over previous
//
#include <hip/hip_runtime.h>
#include <hip/hip_bf16.h>
#include <stdint.h>

typedef __bf16 bf16;
typedef __bf16 bf16x8 __attribute__((ext_vector_type(8)));
typedef __bf16 bf16x4 __attribute__((ext_vector_type(4)));
typedef float  f32x4  __attribute__((ext_vector_type(4)));

#define LDS_PTR(p) ((__attribute__((address_space(3))) uint32_t*)(p))
#define GLB_PTR(p) ((const __attribute__((address_space(1))) uint32_t*)(p))

static constexpr int BATCH = 4, SEQ = 4096, DMODEL = 1024;
static constexpr int DI = 2048;
static constexpr int MTOK = BATCH * SEQ;   // 16384 tokens

enum { EPI_SPLIT = 0, EPI_PLAIN = 1, EPI_GATE = 2, EPI_RES = 3, EPI_F32S = 4 };

// ---------------------------------------------------------------------------
// 128x128-tile bf16 GEMM (m97 structure) — the proven workhorse (~780 TF).
// SPLITK: blockIdx.x = K-split, blockIdx.y = m-tile, blockIdx.z = n-tile.
// KEXT: one extra K-tile staged from side buffers Ax[M][64] / Bx[N][64]
//   (bf16, cols>=16 zeroed) — rank-16 z_a correction inside the K-loop at
//   zero register/occupancy cost (round-6 lesson: epilogue fusion cost
//   VGPR 80->116, occupancy 28->21, -50us).
// EPI_GATE: y2 = gate * (acc + bias[n]); out write-only.
// ---------------------------------------------------------------------------
template <int EPI, bool SPLITK = false, bool KEXT = false>
__global__ __launch_bounds__(256) void gemm_bt(
    const bf16* __restrict__ Aact, const bf16* __restrict__ W,
    const float* __restrict__ bias,
    bf16* __restrict__ out0, bf16* __restrict__ out1,
    const bf16* __restrict__ gate,
    float* __restrict__ outf, const float* __restrict__ resid,
    int N, int K, int ldC, int col_off,
    const bf16* __restrict__ Ax, const bf16* __restrict__ Bx)
{
  __shared__ __align__(16) bf16 sA[128 * 64];
  __shared__ __align__(16) bf16 sB[128 * 64];
  const int tid  = threadIdx.x;
  int n0, m0, kbeg, kend;
  size_t out_off = 0;
  if (SPLITK) {
    n0 = blockIdx.z * 128;
    m0 = blockIdx.y * 128;
    const int kh = K / gridDim.x;
    kbeg = blockIdx.x * kh; kend = kbeg + kh;
    out_off = (EPI == EPI_F32S) ? (size_t)blockIdx.x * (size_t)col_off
                                : (size_t)blockIdx.x * ((size_t)MTOK * 128);
  } else {
    const int nT  = gridDim.x;
    const int lin = blockIdx.y * nT + blockIdx.x;
    const int grp = lin / (8 * nT);
    const int within = lin - grp * (8 * nT);
    n0 = (within >> 3) * 128;
    m0 = (grp * 8 + (within & 7)) * 128;
    kbeg = 0; kend = K;
  }
  const int lane = tid & 63;
  const int wv   = tid >> 6;
  const int wr   = wv >> 1, wc = wv & 1;
  const int l15  = lane & 15, quad = lane >> 4;

  f32x4 acc[4][4];
#pragma unroll
  for (int i = 0; i < 4; ++i)
#pragma unroll
    for (int j = 0; j < 4; ++j) acc[i][j] = (f32x4){0.f, 0.f, 0.f, 0.f};

  int rr[4], cb[4];
#pragma unroll
  for (int j = 0; j < 4; ++j) {
    const int s = tid + j * 256;
    rr[j] = s >> 3;
    cb[j] = ((s & 7) ^ (rr[j] & 7)) * 16;
  }

  const char* gA = (const char*)(Aact + (size_t)m0 * K);
  const char* gW = (const char*)(W + (size_t)n0 * K);

  const int ntile = (kend - kbeg) >> 6;
  const int ttot  = KEXT ? ntile + 1 : ntile;
  for (int ti = 0; ti < ttot; ++ti) {
    if (ti) __syncthreads();
    if (!KEXT || ti < ntile) {
      const int k0 = kbeg + ti * 64;
#pragma unroll
      for (int j = 0; j < 4; ++j)
        __builtin_amdgcn_global_load_lds(GLB_PTR(gA + ((size_t)rr[j] * K + k0) * 2 + cb[j]),
                                         LDS_PTR(sA + (tid + j * 256) * 8), 16, 0, 0);
#pragma unroll
      for (int j = 0; j < 4; ++j)
        __builtin_amdgcn_global_load_lds(GLB_PTR(gW + ((size_t)rr[j] * K + k0) * 2 + cb[j]),
                                         LDS_PTR(sB + (tid + j * 256) * 8), 16, 0, 0);
    } else {
#pragma unroll
      for (int j = 0; j < 4; ++j)
        __builtin_amdgcn_global_load_lds(GLB_PTR((const char*)Ax + ((size_t)(m0 + rr[j]) * 64) * 2 + cb[j]),
                                         LDS_PTR(sA + (tid + j * 256) * 8), 16, 0, 0);
#pragma unroll
      for (int j = 0; j < 4; ++j)
        __builtin_amdgcn_global_load_lds(GLB_PTR((const char*)Bx + ((size_t)(n0 + rr[j]) * 64) * 2 + cb[j]),
                                         LDS_PTR(sB + (tid + j * 256) * 8), 16, 0, 0);
    }
    __syncthreads();

#pragma unroll
    for (int h = 0; h < 2; ++h) {
      bf16x8 av[4], bv[4];
#pragma unroll
      for (int t = 0; t < 4; ++t) {
        const int Ra = wr * 64 + t * 16 + l15;
        const int Rb = wc * 64 + t * 16 + l15;
        const int cc = h * 4 + quad;
        av[t] = *(const bf16x8*)(sA + (Ra * 8 + (cc ^ (Ra & 7))) * 8);
        bv[t] = *(const bf16x8*)(sB + (Rb * 8 + (cc ^ (Rb & 7))) * 8);
      }
#pragma unroll
      for (int i = 0; i < 4; ++i)
#pragma unroll
        for (int j = 0; j < 4; ++j)
          acc[i][j] = __builtin_amdgcn_mfma_f32_16x16x32_bf16(av[i], bv[j], acc[i][j], 0, 0, 0);
    }
  }

  bf16*  o0 = out0 + out_off;
  float* of = outf ? outf + out_off : nullptr;
  // epilogue: C/D layout col = lane&15, row = quad*4 + r (m89-verified)
#pragma unroll
  for (int i = 0; i < 4; ++i) {
    const int mbase = m0 + wr * 64 + i * 16 + quad * 4;
#pragma unroll
    for (int j = 0; j < 4; ++j) {
      const int n = n0 + wc * 64 + j * 16 + l15;
      const float bj = bias ? bias[n] : 0.f;
#pragma unroll
      for (int r = 0; r < 4; ++r) {
        const int mm = mbase + r;
        float v = acc[i][j][r] + bj;
        if (EPI == EPI_SPLIT) {
          if (n < DI) o0[(size_t)mm * DI + n] = (bf16)(1.f / (1.f + __expf(-v)));
          else        out1[(size_t)mm * DI + (n - DI)] = (bf16)v;
        } else if (EPI == EPI_PLAIN) {
          o0[(size_t)mm * ldC + col_off + n] = (bf16)v;
        } else if (EPI == EPI_GATE) {
          const float g = (float)gate[(size_t)mm * DI + n];
          o0[(size_t)mm * ldC + n] = (bf16)(v * g);
        } else if (EPI == EPI_F32S) {
          of[(size_t)mm * ldC + n] = v;
        } else {  // EPI_RES: fp32 out + residual
          outf[(size_t)mm * ldC + n] = v + resid[(size_t)mm * ldC + n];
        }
      }
    }
  }
}

// ---------------------------------------------------------------------------
// RMSNorm: one block per token row (1024 fp32 -> 1024 bf16)
// ---------------------------------------------------------------------------
__global__ __launch_bounds__(256) void rmsnorm_kernel(
    const float* __restrict__ x, const float* __restrict__ w, bf16* __restrict__ out)
{
  const int row = blockIdx.x;
  const int tid = threadIdx.x;
  const float4 xv = ((const float4*)(x + (size_t)row * DMODEL))[tid];
  float s = xv.x * xv.x + xv.y * xv.y + xv.z * xv.z + xv.w * xv.w;
#pragma unroll
  for (int o = 32; o; o >>= 1) s += __shfl_xor(s, o);
  __shared__ float red[4];
  if ((tid & 63) == 0) red[tid >> 6] = s;
  __syncthreads();
  const float tot = red[0] + red[1] + red[2] + red[3];
  const float scale = rsqrtf(tot * (1.f / DMODEL) + 1e-6f);
  const float4 wv = ((const float4*)w)[tid];
  bf16x4 o4 = { (bf16)(xv.x * wv.x * scale), (bf16)(xv.y * wv.y * scale),
                (bf16)(xv.z * wv.z * scale), (bf16)(xv.w * wv.w * scale) };
  *(bf16x4*)(out + (size_t)row * DMODEL + tid * 4) = o4;
}

// ---------------------------------------------------------------------------
// 9-tap depthwise conv + silu, 4 channels/thread (bf16x4 loads). TL2=32.
// ---------------------------------------------------------------------------
static constexpr int TL2 = 32;
__global__ __launch_bounds__(256) void conv_kernel(
    const bf16* __restrict__ val,
    const float* __restrict__ sym_k, const float* __restrict__ sym_b,
    bf16* __restrict__ bbuf)
{
  const int d  = (blockIdx.y * 256 + threadIdx.x) * 4;
  const int b  = blockIdx.z;
  const int l0 = blockIdx.x * TL2;
  float wk[9][4], bs[4];
#pragma unroll
  for (int j = 0; j < 4; ++j) {
    bs[j] = sym_b[d + j];
#pragma unroll
    for (int k = 0; k < 9; ++k) wk[k][j] = sym_k[(d + j) * 9 + k];
  }
  const bf16* base = val + (size_t)b * SEQ * DI + d;

  float win[9][4];
#pragma unroll
  for (int j = 0; j < 8; ++j) {
    const int xr = l0 + j - 4;
    if (xr >= 0 && xr < SEQ) {
      bf16x4 v = *(const bf16x4*)(base + (size_t)xr * DI);
#pragma unroll
      for (int c = 0; c < 4; ++c) win[j][c] = (float)v[c];
    } else {
#pragma unroll
      for (int c = 0; c < 4; ++c) win[j][c] = 0.f;
    }
  }
  for (int t = 0; t < TL2; ++t) {
    const int xf = l0 + t + 4;
    if (xf < SEQ) {
      bf16x4 v = *(const bf16x4*)(base + (size_t)xf * DI);
#pragma unroll
      for (int c = 0; c < 4; ++c) win[8][c] = (float)v[c];
    } else {
#pragma unroll
      for (int c = 0; c < 4; ++c) win[8][c] = 0.f;
    }
    float sb[4];
#pragma unroll
    for (int c = 0; c < 4; ++c) sb[c] = bs[c];
#pragma unroll
    for (int k = 0; k < 9; ++k)
#pragma unroll
      for (int c = 0; c < 4; ++c) sb[c] += win[k][c] * wk[k][c];
    bf16x4 o;
#pragma unroll
    for (int c = 0; c < 4; ++c) o[c] = (bf16)(sb[c] / (1.f + __expf(-sb[c])));
    *(bf16x4*)(bbuf + ((size_t)b * SEQ + l0 + t) * DI + d) = o;
#pragma unroll
    for (int k = 0; k < 8; ++k)
#pragma unroll
      for (int c = 0; c < 4; ++c) win[k][c] = win[k + 1][c];
  }
}

// ---------------------------------------------------------------------------
// prep1: everything with no prep-GEMM dependency, one fat kernel.
//   cvt in_w (4096) | cvt hb_w (2048) | cvt out_w (2048) | pw transpose (4096)
//   | t1 (1024) | cvec (1) | bh (4) | wprep (8) | fbcopy (2048)  -> 15373
// ---------------------------------------------------------------------------
__global__ __launch_bounds__(256) void prep1_kernel(
    const float* __restrict__ in_w, const float* __restrict__ hb_w,
    const float* __restrict__ out_w, const float* __restrict__ pw_w,
    const float* __restrict__ Bm, const float* __restrict__ ha_w,
    const float* __restrict__ dwa_b, const float* __restrict__ dwa_k,
    const float* __restrict__ A, const float* __restrict__ pw_b,
    const float* __restrict__ hb_b, const float* __restrict__ fuse_w,
    bf16* __restrict__ in_wbf, bf16* __restrict__ hb_bf,
    bf16* __restrict__ out_bf, bf16* __restrict__ pwT_bf,
    float* __restrict__ T1, float* __restrict__ cvec, float* __restrict__ b_H,
    bf16* __restrict__ Wp, bf16* __restrict__ Fb)
{
  __shared__ float s[32][33];
  __shared__ float red[4][16];
  const int b = blockIdx.x, tid = threadIdx.x;
  if (b < 8192) {
    const float* src; bf16* dst; size_t i;
    if (b < 4096)      { src = in_w;  dst = in_wbf; i = (size_t)b * 256 + tid; }
    else if (b < 6144) { src = hb_w;  dst = hb_bf;  i = (size_t)(b - 4096) * 256 + tid; }
    else               { src = out_w; dst = out_bf; i = (size_t)(b - 6144) * 256 + tid; }
    const float4 v = ((const float4*)src)[i];
    bf16x4 o4 = { (bf16)v.x, (bf16)v.y, (bf16)v.z, (bf16)v.w };
    *(bf16x4*)(dst + 4 * i) = o4;
  } else if (b < 12288) {
    const int q = b - 8192;
    const int d0 = (q & 63) * 32, c0 = (q >> 6) * 32;
    const int r = tid >> 5, x = tid & 31;
#pragma unroll
    for (int rr = r; rr < 32; rr += 8)
      s[rr][x] = pw_w[(size_t)(c0 + rr) * 2048 + d0 + x];
    __syncthreads();
#pragma unroll
    for (int rr = r; rr < 32; rr += 8)
      pwT_bf[(size_t)(d0 + rr) * 2048 + c0 + x] = (bf16)s[x][rr];
  } else if (b < 13312) {
    const int o = b - 12288;
    float acc[16];
#pragma unroll
    for (int ss = 0; ss < 16; ++ss) acc[ss] = 0.f;
    for (int d = tid; d < 2048; d += 256) {
      const float w = ha_w[(size_t)o * 2048 + d];
#pragma unroll
      for (int ss = 0; ss < 16; ++ss) acc[ss] += Bm[ss * 2048 + d] * w;
    }
    const int lane = tid & 63, wv = tid >> 6;
#pragma unroll
    for (int ss = 0; ss < 16; ++ss) {
      float v = acc[ss];
#pragma unroll
      for (int off = 32; off; off >>= 1) v += __shfl_xor(v, off);
      if (lane == ss) red[wv][ss] = v;
    }
    __syncthreads();
    if (tid < 16)
      T1[tid * 1024 + o] = red[0][tid] + red[1][tid] + red[2][tid] + red[3][tid];
  } else if (b == 13312) {
    float acc[16];
#pragma unroll
    for (int ss = 0; ss < 16; ++ss) acc[ss] = 0.f;
    for (int d = tid; d < 2048; d += 256) {
      const float w = dwa_b[d];
#pragma unroll
      for (int ss = 0; ss < 16; ++ss) acc[ss] += w * A[d * 16 + ss];
    }
    const int lane = tid & 63, wv = tid >> 6;
#pragma unroll
    for (int ss = 0; ss < 16; ++ss) {
      float v = acc[ss];
#pragma unroll
      for (int off = 32; off; off >>= 1) v += __shfl_xor(v, off);
      if (lane == ss) red[wv][ss] = v;
    }
    __syncthreads();
    if (tid < 16) cvec[tid] = red[0][tid] + red[1][tid] + red[2][tid] + red[3][tid];
  } else if (b < 13317) {
    const int o = (b - 13313) * 256 + tid;
    float acc = hb_b[o];
    const float* hr = hb_w + (size_t)o * 2048;
    for (int c = 0; c < 2048; c += 4) {
      float4 h = *(const float4*)(hr + c);
      float4 p = *(const float4*)(pw_b + c);
      acc += h.x * p.x + h.y * p.y + h.z * p.z + h.w * p.w;
    }
    b_H[o] = acc;
  } else if (b < 13325) {
    const int d = (b - 13317) * 256 + tid;
    float kk[4], av[16];
#pragma unroll
    for (int k = 0; k < 4; ++k) kk[k] = dwa_k[d * 4 + k];
#pragma unroll
    for (int ss = 0; ss < 16; ++ss) av[ss] = A[d * 16 + ss];
#pragma unroll
    for (int k = 0; k < 4; ++k)
#pragma unroll
      for (int ss = 0; ss < 16; ++ss)
        Wp[(size_t)(k * 16 + ss) * 2048 + d] = (bf16)(kk[k] * av[ss]);
    for (int n = 64; n < 128; ++n) Wp[(size_t)n * 2048 + d] = (bf16)0.f;
  } else {
    const int idx = (b - 13325) * 256 + tid;
    const int n = idx >> 8, o4 = idx & 255;
    float4 v = ((const float4*)(fuse_w + (size_t)n * 2048 + 1024))[o4];
    bf16x4 o = { (bf16)v.x, (bf16)v.y, (bf16)v.z, (bf16)v.w };
    *(bf16x4*)(Fb + (size_t)n * 1024 + o4 * 4) = o;
  }
}

// ---------------------------------------------------------------------------
// htcomb: Ht_bf = bf16(sum of 8 fp32 split-K partials). 2048 blocks.
// ---------------------------------------------------------------------------
__global__ __launch_bounds__(256) void htcomb_kernel(
    const float* __restrict__ Hp, bf16* __restrict__ Ht)
{
  const size_t e4 = (size_t)blockIdx.x * 256 + threadIdx.x;
  float4 a = ((const float4*)Hp)[e4];
#pragma unroll
  for (int k = 1; k < 8; ++k) {
    float4 p = ((const float4*)(Hp + (size_t)k * 2048 * 1024))[e4];
    a.x += p.x; a.y += p.y; a.z += p.z; a.w += p.w;
  }
  bf16x4 o = { (bf16)a.x, (bf16)a.y, (bf16)a.z, (bf16)a.w };
  *(bf16x4*)(Ht + e4 * 4) = o;
}

// ---------------------------------------------------------------------------
// prep_fuse: t2t (512) | biasz (2048) | WB combine (4096). Grid 6656.
//   t2t: 4 threads per (n,s) dot (was 1 thread, 128 blocks = 0.5/CU).
//   WB combine: WB_bf = bf16(WBp0 + WBp1) fp32 split-K partials.
// ---------------------------------------------------------------------------
__global__ __launch_bounds__(256) void prep_fuse_kernel(
    const float* __restrict__ T1, const float* __restrict__ fuse_w,
    const float* __restrict__ fuse_b, const float* __restrict__ ha_b,
    const float* __restrict__ b_H, const float* __restrict__ WBp,
    bf16* __restrict__ T2e, float* __restrict__ bias_z, bf16* __restrict__ WB)
{
  const int b = blockIdx.x, tid = threadIdx.x;
  if (b < 512) {
    // T2e[n][s] = dot(fuse_w[n][0:1024], T1[s][:]); 4 n/block, 4 thr/(n,s)
    const int n = b * 4 + (tid >> 6);
    const int s = (tid >> 2) & 15;
    const int sub = tid & 3;
    const float* fr = fuse_w + (size_t)n * 2048;
    const float* tr = T1 + s * 1024;
    float acc = 0.f;
    for (int o = sub * 4; o < 1024; o += 16) {
      float4 f = *(const float4*)(fr + o);
      float4 t = *(const float4*)(tr + o);
      acc += f.x * t.x + f.y * t.y + f.z * t.z + f.w * t.w;
    }
    acc += __shfl_xor(acc, 1);
    acc += __shfl_xor(acc, 2);
    if (sub == 0) {
      T2e[(size_t)n * 64 + s]      = (bf16)acc;
      T2e[(size_t)n * 64 + s + 16] = (bf16)0.f;
      T2e[(size_t)n * 64 + s + 32] = (bf16)0.f;
      T2e[(size_t)n * 64 + s + 48] = (bf16)0.f;
    }
  } else if (b < 2560) {
    const int n = b - 512;
    const float* fr = fuse_w + (size_t)n * 2048;
    const int o = tid * 4;
    float4 fa = *(const float4*)(fr + o);
    float4 fb = *(const float4*)(fr + 1024 + o);
    float4 ha = *(const float4*)(ha_b + o);
    float4 bh = *(const float4*)(b_H + o);
    float acc = fa.x * ha.x + fa.y * ha.y + fa.z * ha.z + fa.w * ha.w
              + fb.x * bh.x + fb.y * bh.y + fb.z * bh.z + fb.w * bh.w;
#pragma unroll
    for (int off = 32; off; off >>= 1) acc += __shfl_xor(acc, off);
    __shared__ float r4[4];
    if ((tid & 63) == 0) r4[tid >> 6] = acc;
    __syncthreads();
    if (tid == 0) bias_z[n] = fuse_b[n] + r4[0] + r4[1] + r4[2] + r4[3];
  } else {
    const size_t e4 = (size_t)(b - 2560) * 256 + tid;
    float4 p0 = ((const float4*)WBp)[e4];
    float4 p1 = ((const float4*)(WBp + (size_t)2048 * 2048))[e4];
    bf16x4 o = { (bf16)(p0.x + p1.x), (bf16)(p0.y + p1.y),
                 (bf16)(p0.z + p1.z), (bf16)(p0.w + p1.w) };
    *(bf16x4*)(WB + e4 * 4) = o;
  }
}

// ---------------------------------------------------------------------------
// s16_kernel: s16e[tok][s] = cvec[s] + sum_k (P0+P1)[bb, l-1+k, k*16+s]
// bf16 ext-tile layout [MTOK][64], cols 16..63 zero. 2 MB.
// ---------------------------------------------------------------------------
__global__ __launch_bounds__(256) void s16_kernel(
    const bf16* __restrict__ P0, const bf16* __restrict__ P1,
    const float* __restrict__ cvec, bf16* __restrict__ s16e)
{
  const int g = blockIdx.x * 256 + threadIdx.x;
  const int tok = g >> 4, s = g & 15;
  const int l = tok & (SEQ - 1), bb = tok >> 12;
  float acc = cvec[s];
#pragma unroll
  for (int k = 0; k < 4; ++k) {
    const int r = l - 1 + k;
    if ((unsigned)r < (unsigned)SEQ) {
      const size_t idx = ((size_t)bb * SEQ + r) * 128 + k * 16 + s;
      acc += (float)P0[idx] + (float)P1[idx];
    }
  }
  s16e[(size_t)tok * 64 + s]      = (bf16)acc;
  s16e[(size_t)tok * 64 + s + 16] = (bf16)0.f;
  s16e[(size_t)tok * 64 + s + 32] = (bf16)0.f;
  s16e[(size_t)tok * 64 + s + 48] = (bf16)0.f;
}

// ---------------------------------------------------------------------------
extern "C" void kernel_launch(void* const* d_in, const int* in_sizes, int n_in,
                              void* d_out, int out_size, void* d_ws, size_t ws_size,
                              hipStream_t stream)
{
  const float* x      = (const float*)d_in[0];
  const float* norm_w = (const float*)d_in[1];
  const float* in_w   = (const float*)d_in[2];
  const float* in_b   = (const float*)d_in[3];
  const float* dwa_k  = (const float*)d_in[4];
  const float* dwa_b  = (const float*)d_in[5];
  const float* Amat   = (const float*)d_in[6];
  const float* Bm     = (const float*)d_in[7];
  const float* sym_k  = (const float*)d_in[8];
  const float* sym_b  = (const float*)d_in[9];
  const float* pw_w   = (const float*)d_in[10];
  const float* pw_b   = (const float*)d_in[11];
  const float* ha_w   = (const float*)d_in[12];
  const float* ha_b   = (const float*)d_in[13];
  const float* hb_w   = (const float*)d_in[14];
  const float* hb_b   = (const float*)d_in[15];
  const float* fuse_w = (const float*)d_in[16];
  const float* fuse_b = (const float*)d_in[17];
  const float* out_w  = (const float*)d_in[18];
  const float* out_b  = (const float*)d_in[19];
  float* out = (float*)d_out;

  char* ws = (char*)d_ws;
  const size_t MB = 1u << 20, KB = 1u << 10;
  // Overlay plan (peak ~220.9 MB):
  //  R0 [0,64):   in_wbf[0,8) + hnorm[8,40)  ->  bsilu
  //  R1 [64,128): Hpart 8x8MB / WBp 2x16MB (prep)  ->  val  ->  zbuf
  //  R2 [128,192): gate
  //  s16e (2 MB) overlays Fb_bf (dead after WB-GEMM).
  bf16*  in_wbf  = (bf16*)(ws + 0);
  bf16*  hnorm   = (bf16*)(ws + 8 * MB);
  bf16*  bsilu   = (bf16*)(ws + 0);
  float* Hpart   = (float*)(ws + 64 * MB);              // 8 x 8 MB, prep-only
  float* WBp     = (float*)(ws + 64 * MB);              // 2 x 16 MB, prep-only
  bf16*  valp    = (bf16*)(ws + 64 * MB);
  bf16*  zbuf    = (bf16*)(ws + 64 * MB);
  bf16*  gatep   = (bf16*)(ws + 128 * MB);
  bf16*  Pbuf    = (bf16*)(ws + 192 * MB);              // 8 MB (2 split-K parts)
  bf16*  pwT_bf  = (bf16*)(ws + 200 * MB);              // 8 MB (dead after Ht)
  bf16*  WB_bf   = (bf16*)(ws + 200 * MB);              // 8 MB (overlays pwT)
  bf16*  hb_bf   = (bf16*)(ws + 208 * MB);              // 4 MB (dead after Ht)
  bf16*  Fb_bf   = (bf16*)(ws + 208 * MB);              // 4 MB (dead after WB)
  bf16*  s16e    = (bf16*)(ws + 208 * MB);              // 2 MB (overlays Fb)
  bf16*  Ht_bf   = (bf16*)(ws + 212 * MB);              // 4 MB
  bf16*  out_bf  = (bf16*)(ws + 216 * MB);              // 4 MB
  float* T1      = (float*)(ws + 220 * MB);             // 64 KB
  float* cvec    = (float*)(ws + 220 * MB + 64 * KB);   // 64 B
  float* b_H     = (float*)(ws + 220 * MB + 68 * KB);   // 4 KB
  float* bias_z  = (float*)(ws + 220 * MB + 72 * KB);   // 8 KB
  bf16*  Wp      = (bf16*)(ws + 220 * MB + 80 * KB);    // 512 KB
  bf16*  T2e     = (bf16*)(ws + 220 * MB + 592 * KB);   // 256 KB -> 220.83 MB

  // ---- weight prep (5 launches) ----
  prep1_kernel<<<15373, 256, 0, stream>>>(
      in_w, hb_w, out_w, pw_w, Bm, ha_w, dwa_b, dwa_k, Amat, pw_b, hb_b, fuse_w,
      in_wbf, hb_bf, out_bf, pwT_bf, T1, cvec, b_H, Wp, Fb_bf);
  // Ht[d,o] = sum_c pw_w[c,d]*hb_w[o,c] — split-K=8, fp32 partials -> Hpart
  gemm_bt<EPI_F32S, true><<<dim3(8, 16, 8), 256, 0, stream>>>(
      pwT_bf, hb_bf, nullptr, nullptr, nullptr, nullptr, Hpart, nullptr,
      1024, 2048, 1024, 2048 * 1024, nullptr, nullptr);
  htcomb_kernel<<<2048, 256, 0, stream>>>(Hpart, Ht_bf);
  // W_B[n,d] = sum_o F_b[n,o]*Ht[d,o] — split-K=2, fp32 partials -> WBp
  gemm_bt<EPI_F32S, true><<<dim3(2, 16, 16), 256, 0, stream>>>(
      Fb_bf, Ht_bf, nullptr, nullptr, nullptr, nullptr, WBp, nullptr,
      2048, 1024, 2048, 2048 * 2048, nullptr, nullptr);
  prep_fuse_kernel<<<6656, 256, 0, stream>>>(
      T1, fuse_w, fuse_b, ha_b, b_H, WBp, T2e, bias_z, WB_bf);

  // ---- main chain (7 launches) ----
  rmsnorm_kernel<<<MTOK, 256, 0, stream>>>(x, norm_w, hnorm);
  // in-proj: gate = sigmoid(h[:, :DI]), val = h[:, DI:]
  gemm_bt<EPI_SPLIT><<<dim3(32, 128), 256, 0, stream>>>(
      hnorm, in_wbf, in_b, gatep, valp, nullptr, nullptr, nullptr,
      4096, 1024, DI, 0, nullptr, nullptr);
  // 9-tap conv + silu (val -> bsilu, overlays dead in_wbf/hnorm)
  conv_kernel<<<dim3(SEQ / TL2, 2, BATCH), 256, 0, stream>>>(
      valp, sym_k, sym_b, bsilu);
  // skinny P GEMM, split-K=2: P = val @ Wp^T  (N=128 padded)
  gemm_bt<EPI_PLAIN, true><<<dim3(2, 128), 256, 0, stream>>>(
      valp, Wp, nullptr, Pbuf, nullptr, nullptr, nullptr, nullptr,
      128, 2048, 128, 0, nullptr, nullptr);
  // s16 ext tile (2 MB)
  s16_kernel<<<MTOK * 16 / 256, 256, 0, stream>>>(
      Pbuf, Pbuf + (size_t)MTOK * 128, cvec, s16e);
  // B-GEMM with rank-16 K-extension: y2 = gate*(bsilu@W_B^T + s16@T2t^T + bias_z)
  gemm_bt<EPI_GATE, false, true><<<dim3(16, 128), 256, 0, stream>>>(
      bsilu, WB_bf, bias_z, zbuf, nullptr, gatep, nullptr, nullptr,
      2048, 2048, 2048, 0, s16e, T2e);
  // out GEMM + residual -> fp32 d_out
  gemm_bt<EPI_RES><<<dim3(8, 128), 256, 0, stream>>>(
      zbuf, out_bf, out_b, nullptr, nullptr, nullptr, out, x,
      1024, 2048, 1024, 0, nullptr, nullptr);
}